// Round 1
// baseline (31333.847 us; speedup 1.0000x reference)
//
#include <hip/hip_runtime.h>
#include <hip/hip_cooperative_groups.h>

// ---------------------------------------------------------------------------
// Recurrent ReLU net on MI355X.
//   h_{s+1} = relu(h_s @ W^T  [+ injection at sensory cols on micro==0])
//   512 sequential steps; persistent cooperative kernel, W resident in LDS
//   as fp16 hi/lo split (2-product MFMA ~= fp32-accurate W), h state fp16.
// ---------------------------------------------------------------------------

#define N_DIM   2048
#define B_DIM   64
#define T_DIM   128
#define K_MICRO 4
#define NSENS   256
#define NOUT    128

#define NWG          128          // workgroups in main kernel (1 per CU, half chip)
#define CW           16           // output columns owned per WG
#define WROW_PAD     2056         // fp16 elems per LDS W row (pad 8 -> 2-way banks, free)
#define MAIN_THREADS 512          // 8 waves, each owns a 256-wide K slab
#define SP_STRIDE    68           // fp16 scratch row stride (conflict-free)
#define LDS_W_ELEMS  (CW * WROW_PAD)
#define SMEM_MAIN    (2 * LDS_W_ELEMS * 2 + 8 * 16 * SP_STRIDE * 2)  // 148,992 B

typedef _Float16 f16x8 __attribute__((ext_vector_type(8)));
typedef _Float16 f16x4 __attribute__((ext_vector_type(4)));
typedef float    f32x4 __attribute__((ext_vector_type(4)));

namespace cg = cooperative_groups;

// ---------------- setup kernels ----------------

__global__ void k_inv_init(int* inv_sens, int* inv_out) {
    int i = blockIdx.x * blockDim.x + threadIdx.x;
    if (i < N_DIM) { inv_sens[i] = -1; inv_out[i] = -1; }
}

__global__ void k_inv_scatter(int* inv_sens, int* inv_out,
                              const int* sidx, const int* oidx) {
    int i = threadIdx.x;
    if (i < NSENS) inv_sens[sidx[i]] = i;
    if (i < NOUT)  inv_out[oidx[i]] = i;
}

// inj[t][s][b] = sum_i x[b][t][i]*W_in[s][i] + b_in[s]
__global__ void k_inj(float* __restrict__ inj, const float* __restrict__ inputs,
                      const float* __restrict__ W_in, const float* __restrict__ b_in) {
    int idx = blockIdx.x * blockDim.x + threadIdx.x;   // T*NSENS*B exact
    int b = idx & 63, s = (idx >> 6) & 255, t = idx >> 14;
    float acc = b_in[s];
#pragma unroll
    for (int i2 = 0; i2 < 4; ++i2)
        acc += inputs[(b * T_DIM + t) * 4 + i2] * W_in[s * 4 + i2];
    inj[idx] = acc;
}

// ---------------- main persistent kernel ----------------

__global__ __launch_bounds__(MAIN_THREADS, 2)
void rnn_main(const float* __restrict__ W_rec, const float* __restrict__ inj,
              const int* __restrict__ inv_sens, const int* __restrict__ inv_out,
              _Float16* __restrict__ h0, _Float16* __restrict__ h1,
              _Float16* __restrict__ hc /* [T][NOUT][B] */)
{
    extern __shared__ char smem[];
    _Float16* w_hi = (_Float16*)smem;                 // [CW][WROW_PAD]
    _Float16* w_lo = w_hi + LDS_W_ELEMS;              // [CW][WROW_PAD]
    _Float16* sp   = w_lo + LDS_W_ELEMS;              // [8 waves][16 jl][SP_STRIDE]

    const int tid   = threadIdx.x;
    const int wg    = blockIdx.x;
    const int jbase = wg * CW;

    // ---- stage this WG's 16 W rows into LDS as fp16 hi + 4096*lo ----
    for (int jj = 0; jj < CW; ++jj) {
        const float4 w4 = ((const float4*)(W_rec + (size_t)(jbase + jj) * N_DIM))[tid];
        const int kb = tid * 4;
        float wvals[4] = {w4.x, w4.y, w4.z, w4.w};
#pragma unroll
        for (int e = 0; e < 4; ++e) {
            const float w = wvals[e];
            const _Float16 hi = (_Float16)w;
            const _Float16 lo = (_Float16)((w - (float)hi) * 4096.0f);
            w_hi[jj * WROW_PAD + kb + e] = hi;
            w_lo[jj * WROW_PAD + kb + e] = lo;
        }
    }
    // ---- zero initial h state ----
    for (int i = wg * MAIN_THREADS + tid; i < B_DIM * N_DIM; i += NWG * MAIN_THREADS)
        h0[i] = (_Float16)0.0f;

    const int lane = tid & 63;
    const int wv   = tid >> 6;       // wave id 0..7 = K-slab
    const int lrow = lane & 15;      // m (batch) / n (col) within 16-tile
    const int quad = lane >> 4;      // k sub-chunk selector

    // per-epilogue-slot injection/readout column maps (fixed for whole kernel)
    int ep_s[2], ep_u[2];
#pragma unroll
    for (int rep = 0; rep < 2; ++rep) {
        const int jl = (rep * MAIN_THREADS + tid) & 15;
        ep_s[rep] = inv_sens[jbase + jl];
        ep_u[rep] = inv_out[jbase + jl];
    }

    cg::grid_group grid = cg::this_grid();
    __threadfence();
    grid.sync();
    __threadfence();

    _Float16* bufs[2] = {h0, h1};
    const int k0 = wv * (N_DIM / 8);          // this wave's 256-wide K slab

    for (int step = 0; step < T_DIM * K_MICRO; ++step) {
        const int t = step >> 2, micro = step & 3;
        const _Float16* __restrict__ hcur  = bufs[step & 1];
        _Float16* __restrict__       hnext = bufs[(step & 1) ^ 1];

        f32x4 acch[4], accl[4];
#pragma unroll
        for (int mt = 0; mt < 4; ++mt) {
            acch[mt] = (f32x4){0.f, 0.f, 0.f, 0.f};
            accl[mt] = (f32x4){0.f, 0.f, 0.f, 0.f};
        }

        const _Float16* wh = w_hi + lrow * WROW_PAD + k0 + quad * 8;
        const _Float16* wl = w_lo + lrow * WROW_PAD + k0 + quad * 8;
        const _Float16* ha = hcur + lrow * N_DIM + k0 + quad * 8;

#pragma unroll
        for (int ks = 0; ks < 8; ++ks) {
            const f16x8 bh = *(const f16x8*)(wh + ks * 32);
            const f16x8 bl = *(const f16x8*)(wl + ks * 32);
#pragma unroll
            for (int mt = 0; mt < 4; ++mt) {
                const f16x8 a = *(const f16x8*)(ha + mt * 16 * N_DIM + ks * 32);
                acch[mt] = __builtin_amdgcn_mfma_f32_16x16x32_f16(a, bh, acch[mt], 0, 0, 0);
                accl[mt] = __builtin_amdgcn_mfma_f32_16x16x32_f16(a, bl, accl[mt], 0, 0, 0);
            }
        }

        // write this wave's K-slab partial (hi + lo/4096) to LDS scratch
#pragma unroll
        for (int mt = 0; mt < 4; ++mt) {
            f16x4 pv;
#pragma unroll
            for (int r = 0; r < 4; ++r)
                pv[r] = (_Float16)(acch[mt][r] + accl[mt][r] * 2.44140625e-4f);
            *(f16x4*)(sp + (wv * 16 + lrow) * SP_STRIDE + mt * 16 + quad * 4) = pv;
        }
        __syncthreads();

        // epilogue: all 512 threads, 2 elements each (b, jl)
#pragma unroll
        for (int rep = 0; rep < 2; ++rep) {
            const int idx = rep * MAIN_THREADS + tid;
            const int b = idx >> 4, jl = idx & 15;
            float v = 0.f;
#pragma unroll
            for (int s8 = 0; s8 < 8; ++s8)
                v += (float)sp[(s8 * 16 + jl) * SP_STRIDE + b];
            if (micro == 0) {
                const int s = ep_s[rep];
                if (s >= 0) v += inj[(t * NSENS + s) * B_DIM + b];
            }
            v = fmaxf(v, 0.0f);
            const _Float16 hv = (_Float16)v;
            hnext[b * N_DIM + jbase + jl] = hv;
            if (micro == 3) {
                const int u = ep_u[rep];
                if (u >= 0) hc[(t * NOUT + u) * B_DIM + b] = hv;
            }
        }
        __threadfence();
        grid.sync();
        __threadfence();
    }
}

// ---------------- final readout: out[b][t][o] = hc[t][:][b] . W_out[o][:] + b_out ----

__global__ __launch_bounds__(128)
void k_readout(float* __restrict__ out, const _Float16* __restrict__ hc,
               const float* __restrict__ W_out, const float* __restrict__ b_out) {
    __shared__ _Float16 sh[NOUT * B_DIM];
    const int t = blockIdx.x, tid = threadIdx.x;
    const unsigned int* src = (const unsigned int*)(hc + (size_t)t * NOUT * B_DIM);
    for (int i = tid; i < NOUT * B_DIM / 2; i += 128)
        ((unsigned int*)sh)[i] = src[i];
    __syncthreads();
    const int o = tid >> 6, b = tid & 63;
    float acc = b_out[o];
#pragma unroll 8
    for (int u = 0; u < NOUT; ++u)
        acc += (float)sh[u * B_DIM + b] * W_out[o * NOUT + u];
    out[(b * T_DIM + t) * 2 + o] = acc;
}

// ---------------- host launch ----------------

extern "C" void kernel_launch(void* const* d_in, const int* in_sizes, int n_in,
                              void* d_out, int out_size, void* d_ws, size_t ws_size,
                              hipStream_t stream) {
    const float* inputs = (const float*)d_in[0];
    const float* W_rec  = (const float*)d_in[1];
    const float* W_in   = (const float*)d_in[2];
    const float* b_in   = (const float*)d_in[3];
    const float* W_out  = (const float*)d_in[4];
    const float* b_out  = (const float*)d_in[5];
    const int*   sidx   = (const int*)d_in[6];
    const int*   oidx   = (const int*)d_in[7];
    // K == 4 hardcoded

    char* ws = (char*)d_ws;
    float*    inj      = (float*)ws;                       // 8,388,608 B
    _Float16* h0       = (_Float16*)(ws + 8388608);        //   262,144 B
    _Float16* h1       = (_Float16*)(ws + 8388608 + 262144);
    _Float16* hc       = (_Float16*)(ws + 8388608 + 2 * 262144);   // 2,097,152 B
    int*      inv_sens = (int*)(ws + 8388608 + 2 * 262144 + 2097152);
    int*      inv_out  = inv_sens + N_DIM;

    k_inv_init<<<(N_DIM + 255) / 256, 256, 0, stream>>>(inv_sens, inv_out);
    k_inv_scatter<<<1, 256, 0, stream>>>(inv_sens, inv_out, sidx, oidx);
    k_inj<<<(T_DIM * NSENS * B_DIM) / 256, 256, 0, stream>>>(inj, inputs, W_in, b_in);

    hipFuncSetAttribute((const void*)rnn_main,
                        hipFuncAttributeMaxDynamicSharedMemorySize, SMEM_MAIN);

    void* args[7];
    const float* a_wrec = W_rec;  const float* a_inj = inj;
    const int* a_is = inv_sens;   const int* a_io = inv_out;
    _Float16* a_h0 = h0;          _Float16* a_h1 = h1;  _Float16* a_hc = hc;
    args[0] = &a_wrec; args[1] = &a_inj; args[2] = &a_is; args[3] = &a_io;
    args[4] = &a_h0;   args[5] = &a_h1;  args[6] = &a_hc;

    hipLaunchCooperativeKernel((const void*)rnn_main, dim3(NWG), dim3(MAIN_THREADS),
                               args, SMEM_MAIN, stream);

    k_readout<<<T_DIM, 128, 0, stream>>>((float*)d_out, hc, W_out, b_out);
}

// Round 2
// 8589.687 us; speedup vs baseline: 3.6478x; 3.6478x over previous
//
#include <hip/hip_runtime.h>

// ---------------------------------------------------------------------------
// Recurrent ReLU net on MI355X.
//   h_{s+1} = relu(h_s @ W^T  [+ injection at sensory cols on micro==0])
//   512 sequential steps; persistent kernel (128 WGs, 1/CU), W resident in
//   LDS as fp16 hi/lo split, h state fp16 exchanged through IF$ via
//   agent-scope relaxed atomics (no cache-wide fences), custom grid barrier.
// ---------------------------------------------------------------------------

#define N_DIM   2048
#define B_DIM   64
#define T_DIM   128
#define K_MICRO 4
#define NSENS   256
#define NOUT    128

#define NWG          128          // 1 WG per CU, half chip (h-broadcast scales with NWG)
#define CW           16           // output columns owned per WG
#define WROW_PAD     2056         // fp16 elems per LDS W row
#define MAIN_THREADS 512          // 8 waves, each owns a 256-wide K slab
#define SP_STRIDE    68           // fp16 scratch row stride
#define LDS_W_ELEMS  (CW * WROW_PAD)
#define SMEM_MAIN    (2 * LDS_W_ELEMS * 2 + 8 * 16 * SP_STRIDE * 2)  // 148,992 B

typedef _Float16 f16x8 __attribute__((ext_vector_type(8)));
typedef _Float16 f16x4 __attribute__((ext_vector_type(4)));
typedef float    f32x4 __attribute__((ext_vector_type(4)));
typedef unsigned long long u64;

// ---------------- setup kernels ----------------

__global__ void k_init(int* inv_sens, int* inv_out, unsigned* bar) {
    int i = blockIdx.x * blockDim.x + threadIdx.x;
    if (i < N_DIM) { inv_sens[i] = -1; inv_out[i] = -1; }
    if (i < 64) bar[i] = 0u;        // barrier cnt (bar[0]) + gen (bar[32]) lines
}

__global__ void k_inv_scatter(int* inv_sens, int* inv_out,
                              const int* sidx, const int* oidx) {
    int i = threadIdx.x;
    if (i < NSENS) inv_sens[sidx[i]] = i;
    if (i < NOUT)  inv_out[oidx[i]] = i;
}

// inj[t][s][b] = sum_i x[b][t][i]*W_in[s][i] + b_in[s]
__global__ void k_inj(float* __restrict__ inj, const float* __restrict__ inputs,
                      const float* __restrict__ W_in, const float* __restrict__ b_in) {
    int idx = blockIdx.x * blockDim.x + threadIdx.x;   // T*NSENS*B exact
    int b = idx & 63, s = (idx >> 6) & 255, t = idx >> 14;
    float acc = b_in[s];
#pragma unroll
    for (int i2 = 0; i2 < 4; ++i2)
        acc += inputs[(b * T_DIM + t) * 4 + i2] * W_in[s * 4 + i2];
    inj[idx] = acc;
}

// ---------------- device-coherent h access (bypass non-coherent L2s) -------

__device__ __forceinline__ f16x8 load_h8(const _Float16* p) {
    union { u64 u[2]; f16x8 v; } x;
    const u64* q = (const u64*)p;
    x.u[0] = __hip_atomic_load(q,     __ATOMIC_RELAXED, __HIP_MEMORY_SCOPE_AGENT);
    x.u[1] = __hip_atomic_load(q + 1, __ATOMIC_RELAXED, __HIP_MEMORY_SCOPE_AGENT);
    return x.v;
}

// custom grid barrier: one arriver/spinner thread per WG.
// __syncthreads drains each wave's vmcnt; h stores are agent-scope
// write-through, so vmcnt(0) == globally visible (release at IF$).
__device__ __forceinline__ void grid_bar(unsigned* cnt, unsigned* gen, unsigned phase) {
    __syncthreads();
    if (threadIdx.x == 0) {
        unsigned old = __hip_atomic_fetch_add(cnt, 1u, __ATOMIC_RELAXED,
                                              __HIP_MEMORY_SCOPE_AGENT);
        if (old == (phase + 1u) * NWG - 1u) {
            __hip_atomic_store(gen, phase + 1u, __ATOMIC_RELAXED,
                               __HIP_MEMORY_SCOPE_AGENT);
        } else {
            while (__hip_atomic_load(gen, __ATOMIC_RELAXED,
                                     __HIP_MEMORY_SCOPE_AGENT) <= phase) {}
        }
    }
    __syncthreads();
}

// ---------------- main persistent kernel ----------------

__global__ __launch_bounds__(MAIN_THREADS, 2)
void rnn_main(const float* __restrict__ W_rec, const float* __restrict__ inj,
              const int* __restrict__ inv_sens, const int* __restrict__ inv_out,
              _Float16* __restrict__ h0, _Float16* __restrict__ h1,
              _Float16* __restrict__ hc /* [T][NOUT][B] */,
              unsigned* __restrict__ bar)
{
    extern __shared__ char smem[];
    _Float16* w_hi = (_Float16*)smem;                 // [CW][WROW_PAD]
    _Float16* w_lo = w_hi + LDS_W_ELEMS;              // [CW][WROW_PAD]
    _Float16* sp   = w_lo + LDS_W_ELEMS;              // [8 waves][16 jl][SP_STRIDE]

    unsigned* bar_cnt = bar;
    unsigned* bar_gen = bar + 32;                     // separate 128-B line

    const int tid   = threadIdx.x;
    const int wg    = blockIdx.x;
    const int jbase = wg * CW;

    // ---- stage this WG's 16 W rows into LDS as fp16 hi + 4096*lo ----
    for (int jj = 0; jj < CW; ++jj) {
        const float4 w4 = ((const float4*)(W_rec + (size_t)(jbase + jj) * N_DIM))[tid];
        const int kb = tid * 4;
        float wvals[4] = {w4.x, w4.y, w4.z, w4.w};
#pragma unroll
        for (int e = 0; e < 4; ++e) {
            const float w = wvals[e];
            const _Float16 hi = (_Float16)w;
            const _Float16 lo = (_Float16)((w - (float)hi) * 4096.0f);
            w_hi[jj * WROW_PAD + kb + e] = hi;
            w_lo[jj * WROW_PAD + kb + e] = lo;
        }
    }
    // ---- zero initial h state (agent-coherent stores) ----
    for (int i = wg * MAIN_THREADS + tid; i < B_DIM * N_DIM / 2; i += NWG * MAIN_THREADS)
        __hip_atomic_store((unsigned*)h0 + i, 0u, __ATOMIC_RELAXED,
                           __HIP_MEMORY_SCOPE_AGENT);

    const int lane = tid & 63;
    const int wv   = tid >> 6;       // wave id 0..7 = K-slab
    const int lrow = lane & 15;      // n (col) within 16-tile for B; m for A
    const int quad = lane >> 4;      // k sub-chunk selector

    // epilogue mapping: thread -> (b, jl pair)
    const int ep_b  = tid >> 3;          // 0..63
    const int ep_j0 = (tid & 7) * 2;     // jl, jl+1
    const int ep_sA = inv_sens[jbase + ep_j0];
    const int ep_sB = inv_sens[jbase + ep_j0 + 1];
    const int ep_uA = inv_out[jbase + ep_j0];
    const int ep_uB = inv_out[jbase + ep_j0 + 1];

    grid_bar(bar_cnt, bar_gen, 0);       // h0 init visible everywhere

    _Float16* bufs[2] = {h0, h1};
    const int k0 = wv * (N_DIM / 8);     // this wave's 256-wide K slab

    for (int step = 0; step < T_DIM * K_MICRO; ++step) {
        const int t = step >> 2, micro = step & 3;
        const _Float16* __restrict__ hcur  = bufs[step & 1];
        _Float16* __restrict__       hnext = bufs[(step & 1) ^ 1];

        f32x4 acch[4], accl[4];
#pragma unroll
        for (int mt = 0; mt < 4; ++mt) {
            acch[mt] = (f32x4){0.f, 0.f, 0.f, 0.f};
            accl[mt] = (f32x4){0.f, 0.f, 0.f, 0.f};
        }

        const _Float16* wh = w_hi + lrow * WROW_PAD + k0 + quad * 8;
        const _Float16* wl = w_lo + lrow * WROW_PAD + k0 + quad * 8;
        const _Float16* ha = hcur + lrow * N_DIM + k0 + quad * 8;

#pragma unroll
        for (int ks = 0; ks < 8; ++ks) {
            const f16x8 bh = *(const f16x8*)(wh + ks * 32);
            const f16x8 bl = *(const f16x8*)(wl + ks * 32);
#pragma unroll
            for (int mt = 0; mt < 4; ++mt) {
                const f16x8 a = load_h8(ha + mt * 16 * N_DIM + ks * 32);
                acch[mt] = __builtin_amdgcn_mfma_f32_16x16x32_f16(a, bh, acch[mt], 0, 0, 0);
                accl[mt] = __builtin_amdgcn_mfma_f32_16x16x32_f16(a, bl, accl[mt], 0, 0, 0);
            }
        }

        // write this wave's K-slab partial (hi + lo/4096) to LDS scratch
#pragma unroll
        for (int mt = 0; mt < 4; ++mt) {
            f16x4 pv;
#pragma unroll
            for (int r = 0; r < 4; ++r)
                pv[r] = (_Float16)(acch[mt][r] + accl[mt][r] * 2.44140625e-4f);
            *(f16x4*)(sp + (wv * 16 + lrow) * SP_STRIDE + mt * 16 + quad * 4) = pv;
        }
        __syncthreads();

        // epilogue: thread -> (b, jl pair); conflict-free sp reads, 4-B store
        {
            float vA = 0.f, vB = 0.f;
#pragma unroll
            for (int s8 = 0; s8 < 8; ++s8) {
                vA += (float)sp[(s8 * 16 + ep_j0    ) * SP_STRIDE + ep_b];
                vB += (float)sp[(s8 * 16 + ep_j0 + 1) * SP_STRIDE + ep_b];
            }
            if (micro == 0) {
                if (ep_sA >= 0) vA += inj[(t * NSENS + ep_sA) * B_DIM + ep_b];
                if (ep_sB >= 0) vB += inj[(t * NSENS + ep_sB) * B_DIM + ep_b];
            }
            union { _Float16 h[2]; unsigned u; } pk;
            pk.h[0] = (_Float16)fmaxf(vA, 0.0f);
            pk.h[1] = (_Float16)fmaxf(vB, 0.0f);
            __hip_atomic_store((unsigned*)(hnext + ep_b * N_DIM + jbase + ep_j0),
                               pk.u, __ATOMIC_RELAXED, __HIP_MEMORY_SCOPE_AGENT);
            if (micro == 3) {
                if (ep_uA >= 0) hc[(t * NOUT + ep_uA) * B_DIM + ep_b] = pk.h[0];
                if (ep_uB >= 0) hc[(t * NOUT + ep_uB) * B_DIM + ep_b] = pk.h[1];
            }
        }
        grid_bar(bar_cnt, bar_gen, 1u + step);
    }
}

// ---------------- final readout: out[b][t][o] = hc[t][:][b] . W_out[o][:] + b_out ----

__global__ __launch_bounds__(128)
void k_readout(float* __restrict__ out, const _Float16* __restrict__ hc,
               const float* __restrict__ W_out, const float* __restrict__ b_out) {
    __shared__ _Float16 sh[NOUT * B_DIM];
    const int t = blockIdx.x, tid = threadIdx.x;
    const unsigned int* src = (const unsigned int*)(hc + (size_t)t * NOUT * B_DIM);
    for (int i = tid; i < NOUT * B_DIM / 2; i += 128)
        ((unsigned int*)sh)[i] = src[i];
    __syncthreads();
    const int o = tid >> 6, b = tid & 63;
    float acc = b_out[o];
#pragma unroll 8
    for (int u = 0; u < NOUT; ++u)
        acc += (float)sh[u * B_DIM + b] * W_out[o * NOUT + u];
    out[(b * T_DIM + t) * 2 + o] = acc;
}

// ---------------- host launch ----------------

extern "C" void kernel_launch(void* const* d_in, const int* in_sizes, int n_in,
                              void* d_out, int out_size, void* d_ws, size_t ws_size,
                              hipStream_t stream) {
    const float* inputs = (const float*)d_in[0];
    const float* W_rec  = (const float*)d_in[1];
    const float* W_in   = (const float*)d_in[2];
    const float* b_in   = (const float*)d_in[3];
    const float* W_out  = (const float*)d_in[4];
    const float* b_out  = (const float*)d_in[5];
    const int*   sidx   = (const int*)d_in[6];
    const int*   oidx   = (const int*)d_in[7];

    char* ws = (char*)d_ws;
    float*    inj      = (float*)ws;                               // 8,388,608 B
    _Float16* h0       = (_Float16*)(ws + 8388608);                //   262,144 B
    _Float16* h1       = (_Float16*)(ws + 8388608 + 262144);
    _Float16* hc       = (_Float16*)(ws + 8388608 + 2 * 262144);   // 2,097,152 B
    int*      inv_sens = (int*)(ws + 8388608 + 2 * 262144 + 2097152);
    int*      inv_out  = inv_sens + N_DIM;
    unsigned* bar      = (unsigned*)(inv_out + N_DIM);             // 256 B

    k_init<<<(N_DIM + 255) / 256, 256, 0, stream>>>(inv_sens, inv_out, bar);
    k_inv_scatter<<<1, 256, 0, stream>>>(inv_sens, inv_out, sidx, oidx);
    k_inj<<<(T_DIM * NSENS * B_DIM) / 256, 256, 0, stream>>>(inj, inputs, W_in, b_in);

    hipFuncSetAttribute((const void*)rnn_main,
                        hipFuncAttributeMaxDynamicSharedMemorySize, SMEM_MAIN);

    rnn_main<<<NWG, MAIN_THREADS, SMEM_MAIN, stream>>>(
        W_rec, inj, inv_sens, inv_out, h0, h1, hc, bar);

    k_readout<<<T_DIM, 128, 0, stream>>>((float*)d_out, hc, W_out, b_out);
}

// Round 3
// 3557.071 us; speedup vs baseline: 8.8089x; 2.4148x over previous
//
#include <hip/hip_runtime.h>

// ---------------------------------------------------------------------------
// Recurrent ReLU net on MI355X.
//   h_{s+1} = relu(h_s @ W^T  [+ injection at sensory cols on micro==0])
//   512 sequential steps; persistent kernel (128 WGs, 1/CU), W resident in
//   LDS as fp16 hi/lo split. h state fp16 in MFMA A-fragment layout,
//   exchanged through the coherence point via agent-scope relaxed atomics.
//   Grid sync = distributed per-WG flag barrier (no atomic RMW contention).
// ---------------------------------------------------------------------------

#define N_DIM   2048
#define B_DIM   64
#define T_DIM   128
#define K_MICRO 4
#define NSENS   256
#define NOUT    128

#define NWG          128          // 1 WG per CU, half chip (h-broadcast scales with NWG)
#define CW           16           // output columns owned per WG
#define WROW_PAD     2056         // fp16 elems per LDS W row
#define MAIN_THREADS 512          // 8 waves, each owns a 256-wide K slab
#define SP_STRIDE    68           // fp16 scratch row stride
#define LDS_W_ELEMS  (CW * WROW_PAD)
#define SMEM_MAIN    (2 * LDS_W_ELEMS * 2 + 8 * 16 * SP_STRIDE * 2)  // 148,992 B
#define FLAG_STRIDE  32           // u32 per flag line (128 B)

typedef _Float16 f16x8 __attribute__((ext_vector_type(8)));
typedef _Float16 f16x4 __attribute__((ext_vector_type(4)));
typedef float    f32x4 __attribute__((ext_vector_type(4)));
typedef unsigned long long u64;

// ---------------- setup kernels ----------------

__global__ void k_init(int* inv_sens, int* inv_out, unsigned* flags) {
    int i = blockIdx.x * blockDim.x + threadIdx.x;   // 4096 threads
    if (i < N_DIM) { inv_sens[i] = -1; inv_out[i] = -1; }
    if (i < NWG * FLAG_STRIDE) flags[i] = 0u;
}

__global__ void k_inv_scatter(int* inv_sens, int* inv_out,
                              const int* sidx, const int* oidx) {
    int i = threadIdx.x;
    if (i < NSENS) inv_sens[sidx[i]] = i;
    if (i < NOUT)  inv_out[oidx[i]] = i;
}

// inj[t][s][b] = sum_i x[b][t][i]*W_in[s][i] + b_in[s]
__global__ void k_inj(float* __restrict__ inj, const float* __restrict__ inputs,
                      const float* __restrict__ W_in, const float* __restrict__ b_in) {
    int idx = blockIdx.x * blockDim.x + threadIdx.x;   // T*NSENS*B exact
    int b = idx & 63, s = (idx >> 6) & 255, t = idx >> 14;
    float acc = b_in[s];
#pragma unroll
    for (int i2 = 0; i2 < 4; ++i2)
        acc += inputs[(b * T_DIM + t) * 4 + i2] * W_in[s * 4 + i2];
    inj[idx] = acc;
}

// ---------------- device-coherent h access (bypass non-coherent L2s) -------

__device__ __forceinline__ f16x8 load_h8(const _Float16* p) {
    union { u64 u[2]; f16x8 v; } x;
    const u64* q = (const u64*)p;
    x.u[0] = __hip_atomic_load(q,     __ATOMIC_RELAXED, __HIP_MEMORY_SCOPE_AGENT);
    x.u[1] = __hip_atomic_load(q + 1, __ATOMIC_RELAXED, __HIP_MEMORY_SCOPE_AGENT);
    return x.v;
}

// distributed flag barrier: WG i publishes flags[i*FLAG_STRIDE] = target after
// __syncthreads (whose s_waitcnt vmcnt(0) drains the write-through h stores =
// release at the coherence point); threads 0..NWG-1 poll one flag each.
__device__ __forceinline__ void grid_bar(unsigned* flags, unsigned target) {
    __syncthreads();
    if (threadIdx.x == 0)
        __hip_atomic_store(flags + blockIdx.x * FLAG_STRIDE, target,
                           __ATOMIC_RELAXED, __HIP_MEMORY_SCOPE_AGENT);
    if (threadIdx.x < NWG) {
        while (__hip_atomic_load(flags + threadIdx.x * FLAG_STRIDE,
                                 __ATOMIC_RELAXED, __HIP_MEMORY_SCOPE_AGENT) < target) {}
    }
    __syncthreads();
}

// ---------------- main persistent kernel ----------------
// h buffers hold fp16 in MFMA A-fragment order:
//   elem (b, j):  m_tile=b>>4, m_in=b&15, kt=j>>5, quad=(j>>3)&3, r=j&7
//   f16 offset = ((m_tile*64 + kt) << 9) + ((quad*16 + m_in) << 3) + r
// so a wave's A-fragment load for (m_tile, kt) is hbuf[(m_tile*64+kt)*512 + lane*8],
// a single fully-coalesced 1 KB transaction.

__global__ __launch_bounds__(MAIN_THREADS, 2)
void rnn_main(const float* __restrict__ W_rec, const float* __restrict__ inj,
              const int* __restrict__ inv_sens, const int* __restrict__ inv_out,
              _Float16* __restrict__ h0, _Float16* __restrict__ h1,
              _Float16* __restrict__ hc /* [T][NOUT][B] */,
              unsigned* __restrict__ flags)
{
    extern __shared__ char smem[];
    _Float16* w_hi = (_Float16*)smem;                 // [CW][WROW_PAD]
    _Float16* w_lo = w_hi + LDS_W_ELEMS;              // [CW][WROW_PAD]
    _Float16* sp   = w_lo + LDS_W_ELEMS;              // [8 waves][16 jl][SP_STRIDE]

    const int tid   = threadIdx.x;
    const int wg    = blockIdx.x;
    const int jbase = wg * CW;

    // ---- stage this WG's 16 W rows into LDS as fp16 hi + 4096*lo ----
    for (int jj = 0; jj < CW; ++jj) {
        const float4 w4 = ((const float4*)(W_rec + (size_t)(jbase + jj) * N_DIM))[tid];
        const int kb = tid * 4;
        float wvals[4] = {w4.x, w4.y, w4.z, w4.w};
#pragma unroll
        for (int e = 0; e < 4; ++e) {
            const float w = wvals[e];
            const _Float16 hi = (_Float16)w;
            const _Float16 lo = (_Float16)((w - (float)hi) * 4096.0f);
            w_hi[jj * WROW_PAD + kb + e] = hi;
            w_lo[jj * WROW_PAD + kb + e] = lo;
        }
    }
    // ---- zero initial h state (agent-coherent stores) ----
    for (int i = wg * MAIN_THREADS + tid; i < B_DIM * N_DIM / 2; i += NWG * MAIN_THREADS)
        __hip_atomic_store((unsigned*)h0 + i, 0u, __ATOMIC_RELAXED,
                           __HIP_MEMORY_SCOPE_AGENT);

    const int lane = tid & 63;
    const int wv   = tid >> 6;       // wave id 0..7 = K-slab (k tiles wv*8..wv*8+7)
    const int lrow = lane & 15;
    const int quad = lane >> 4;

    // epilogue mapping: thread -> (b, jl pair); h-fragment store offset
    const int ep_b  = tid >> 3;          // 0..63
    const int ep_j0 = (tid & 7) * 2;     // jl, jl+1 (even)
    const int ep_sA = inv_sens[jbase + ep_j0];
    const int ep_sB = inv_sens[jbase + ep_j0 + 1];
    const int ep_uA = inv_out[jbase + ep_j0];
    const int ep_uB = inv_out[jbase + ep_j0 + 1];
    const int ep_j  = jbase + ep_j0;     // global col, even
    const int ep_off = (((ep_b >> 4) * 64 + (ep_j >> 5)) << 9)
                     + (((((ep_j >> 3) & 3) * 16) + (ep_b & 15)) << 3) + (ep_j & 7);

    grid_bar(flags, 1u);                 // h0 init visible everywhere

    _Float16* bufs[2] = {h0, h1};

    for (int step = 0; step < T_DIM * K_MICRO; ++step) {
        const int t = step >> 2, micro = step & 3;
        const _Float16* __restrict__ hcur  = bufs[step & 1];
        _Float16* __restrict__       hnext = bufs[(step & 1) ^ 1];

        // ---- issue ALL 32 A-fragment loads up front (32 KB in flight/wave) ----
        f16x8 A[8][4];
#pragma unroll
        for (int ks = 0; ks < 8; ++ks)
#pragma unroll
            for (int mt = 0; mt < 4; ++mt)
                A[ks][mt] = load_h8(hcur + (((mt * 64 + wv * 8 + ks) << 9) + lane * 8));

        f32x4 acch[4], accl[4];
#pragma unroll
        for (int mt = 0; mt < 4; ++mt) {
            acch[mt] = (f32x4){0.f, 0.f, 0.f, 0.f};
            accl[mt] = (f32x4){0.f, 0.f, 0.f, 0.f};
        }

        const _Float16* wh = w_hi + lrow * WROW_PAD + wv * 256 + quad * 8;
        const _Float16* wl = w_lo + lrow * WROW_PAD + wv * 256 + quad * 8;

#pragma unroll
        for (int ks = 0; ks < 8; ++ks) {
            const f16x8 bh = *(const f16x8*)(wh + ks * 32);
            const f16x8 bl = *(const f16x8*)(wl + ks * 32);
#pragma unroll
            for (int mt = 0; mt < 4; ++mt) {
                acch[mt] = __builtin_amdgcn_mfma_f32_16x16x32_f16(A[ks][mt], bh, acch[mt], 0, 0, 0);
                accl[mt] = __builtin_amdgcn_mfma_f32_16x16x32_f16(A[ks][mt], bl, accl[mt], 0, 0, 0);
            }
        }

        // write this wave's K-slab partial (hi + lo/4096) to LDS scratch
#pragma unroll
        for (int mt = 0; mt < 4; ++mt) {
            f16x4 pv;
#pragma unroll
            for (int r = 0; r < 4; ++r)
                pv[r] = (_Float16)(acch[mt][r] + accl[mt][r] * 2.44140625e-4f);
            *(f16x4*)(sp + (wv * 16 + lrow) * SP_STRIDE + mt * 16 + quad * 4) = pv;
        }
        __syncthreads();

        // epilogue: thread -> (b, jl pair); 4-B fragment-layout store
        {
            float vA = 0.f, vB = 0.f;
#pragma unroll
            for (int s8 = 0; s8 < 8; ++s8) {
                vA += (float)sp[(s8 * 16 + ep_j0    ) * SP_STRIDE + ep_b];
                vB += (float)sp[(s8 * 16 + ep_j0 + 1) * SP_STRIDE + ep_b];
            }
            if (micro == 0) {
                if (ep_sA >= 0) vA += inj[(t * NSENS + ep_sA) * B_DIM + ep_b];
                if (ep_sB >= 0) vB += inj[(t * NSENS + ep_sB) * B_DIM + ep_b];
            }
            union { _Float16 h[2]; unsigned u; } pk;
            pk.h[0] = (_Float16)fmaxf(vA, 0.0f);
            pk.h[1] = (_Float16)fmaxf(vB, 0.0f);
            __hip_atomic_store((unsigned*)(hnext + ep_off),
                               pk.u, __ATOMIC_RELAXED, __HIP_MEMORY_SCOPE_AGENT);
            if (micro == 3) {
                if (ep_uA >= 0) hc[(t * NOUT + ep_uA) * B_DIM + ep_b] = pk.h[0];
                if (ep_uB >= 0) hc[(t * NOUT + ep_uB) * B_DIM + ep_b] = pk.h[1];
            }
        }
        grid_bar(flags, 2u + (unsigned)step);
    }
}

// ---------------- final readout: out[b][t][o] = hc[t][:][b] . W_out[o][:] + b_out ----

__global__ __launch_bounds__(128)
void k_readout(float* __restrict__ out, const _Float16* __restrict__ hc,
               const float* __restrict__ W_out, const float* __restrict__ b_out) {
    __shared__ _Float16 sh[NOUT * B_DIM];
    const int t = blockIdx.x, tid = threadIdx.x;
    const unsigned int* src = (const unsigned int*)(hc + (size_t)t * NOUT * B_DIM);
    for (int i = tid; i < NOUT * B_DIM / 2; i += 128)
        ((unsigned int*)sh)[i] = src[i];
    __syncthreads();
    const int o = tid >> 6, b = tid & 63;
    float acc = b_out[o];
#pragma unroll 8
    for (int u = 0; u < NOUT; ++u)
        acc += (float)sh[u * B_DIM + b] * W_out[o * NOUT + u];
    out[(b * T_DIM + t) * 2 + o] = acc;
}

// ---------------- host launch ----------------

extern "C" void kernel_launch(void* const* d_in, const int* in_sizes, int n_in,
                              void* d_out, int out_size, void* d_ws, size_t ws_size,
                              hipStream_t stream) {
    const float* inputs = (const float*)d_in[0];
    const float* W_rec  = (const float*)d_in[1];
    const float* W_in   = (const float*)d_in[2];
    const float* b_in   = (const float*)d_in[3];
    const float* W_out  = (const float*)d_in[4];
    const float* b_out  = (const float*)d_in[5];
    const int*   sidx   = (const int*)d_in[6];
    const int*   oidx   = (const int*)d_in[7];

    char* ws = (char*)d_ws;
    float*    inj      = (float*)ws;                               // 8,388,608 B
    _Float16* h0       = (_Float16*)(ws + 8388608);                //   262,144 B
    _Float16* h1       = (_Float16*)(ws + 8388608 + 262144);
    _Float16* hc       = (_Float16*)(ws + 8388608 + 2 * 262144);   // 2,097,152 B
    int*      inv_sens = (int*)(ws + 8388608 + 2 * 262144 + 2097152);
    int*      inv_out  = inv_sens + N_DIM;
    unsigned* flags    = (unsigned*)(inv_out + N_DIM);             // 16,384 B

    k_init<<<16, 256, 0, stream>>>(inv_sens, inv_out, flags);
    k_inv_scatter<<<1, 256, 0, stream>>>(inv_sens, inv_out, sidx, oidx);
    k_inj<<<(T_DIM * NSENS * B_DIM) / 256, 256, 0, stream>>>(inj, inputs, W_in, b_in);

    hipFuncSetAttribute((const void*)rnn_main,
                        hipFuncAttributeMaxDynamicSharedMemorySize, SMEM_MAIN);

    rnn_main<<<NWG, MAIN_THREADS, SMEM_MAIN, stream>>>(
        W_rec, inj, inv_sens, inv_out, h0, h1, hc, flags);

    k_readout<<<T_DIM, 128, 0, stream>>>((float*)d_out, hc, W_out, b_out);
}